// Round 5
// baseline (698.570 us; speedup 1.0000x reference)
//
#include <hip/hip_runtime.h>
#include <hip/hip_bf16.h>

#define BB 16384
#define KK 3
#define DD 1024
#define HH 16

typedef __attribute__((ext_vector_type(8))) short bf16x8;
typedef __attribute__((ext_vector_type(4))) float f32x4;
typedef unsigned int u32;

__device__ __forceinline__ void load_lds16(const void* g, void* l) {
  __builtin_amdgcn_global_load_lds(
      (const __attribute__((address_space(1))) u32*)g,
      (__attribute__((address_space(3))) u32*)l,
      16, 0, 0);
}

__device__ __forceinline__ unsigned short f2bf(float f) {
  __hip_bfloat16 h = __float2bfloat16(f);
  unsigned short u;
  __builtin_memcpy(&u, &h, 2);
  return u;
}

__device__ __forceinline__ float bf2f(unsigned short u) {
  union { float f; u32 i; } cv;
  cv.i = ((u32)u) << 16;
  return cv.f;
}

// ---------------------------------------------------------------- cast fp32 -> bf16
__global__ void cast_f32_bf16(const float* __restrict__ in,
                              unsigned short* __restrict__ out, int n4) {
  int stride = gridDim.x * blockDim.x;
  for (int i = blockIdx.x * blockDim.x + threadIdx.x; i < n4; i += stride) {
    float4 v = ((const float4*)in)[i];
    ushort4 o;
    o.x = f2bf(v.x);
    o.y = f2bf(v.y);
    o.z = f2bf(v.z);
    o.w = f2bf(v.w);
    ((ushort4*)out)[i] = o;
  }
}

// ---------------------------------------------------------------- GEMM: C = A @ Bt^T + bias
// 256x256 tile, BK=32, 512 threads = 8 waves (2M x 4N), per-wave 128x64 output.
// 4-slot LDS ring (4 x 32KB). Overlap-structured K-loop (anti-lockstep):
//   iter kt: {issue 8 A-frag ds_reads(kt) | STAGE(kt+3) | vmcnt(8) | sbar |
//             issue 4 B-frag read-ahead(kt+1) | 32 MFMA (compiler counted-lgkm
//             gates on A(kt)/B(kt), B(kt+1) reads overlap MFMA) | sbar}
// No lgkmcnt(0) before MFMA; LDS pipe and MFMA pipe run concurrently.
// B register set alternated via 2x loop unroll (static indexing).
// vmcnt(8) steady state = 3 tiles in flight; tail 4/0.
template <bool OUT_F32>
__global__ __launch_bounds__(512, 2)
void gemm256(const __hip_bfloat16* __restrict__ A,
             const __hip_bfloat16* __restrict__ Bt,
             const float* __restrict__ bias,
             void* __restrict__ Cout,
             int M, int N, int K) {
  __shared__ __align__(128) char lds[131072];

  const int nTn = N >> 8;
  const int nwg = (M >> 8) * nTn;
  int bid = blockIdx.x;
  bid = (bid & 7) * (nwg >> 3) + (bid >> 3);  // bijective XCD swizzle (nwg%8==0)
  const int tm = bid / nTn;
  const int tn = bid % nTn;

  const int tid = threadIdx.x;
  const int l = tid & 63;
  const int w = tid >> 6;
  const int wm = w >> 2;   // 0..1
  const int wn = w & 3;    // 0..3
  const int l15 = l & 15;
  const int g = l >> 4;    // k-chunk group 0..3
  const int l7 = l15 & 7;

  // fragment-read byte offsets inside a slot (layout verified in R3, conflicts=0)
  const int aBase = (l15 << 7) + (((wm << 2) + g) ^ l7) * 16;
  const int bBase = 16384 + ((((wn & 1) << 6) + l15) << 7) +
                    ((((wn >> 1) << 2) + g) ^ l7) * 16;

  // staging geometry (dest linear, source pre-swizzled: phys chunk = q ^ (line&7))
  const size_t strideK = (size_t)K * 2;
  const char* Ab = (const char*)A + (size_t)tm * 256 * strideK;
  const char* Bb = (const char*)Bt + (size_t)tn * 256 * strideK;
  const int q = (tid & 7) ^ ((tid >> 3) & 7);
  const size_t g0 = (size_t)((q >> 2) * 128 + (tid >> 3)) * strideK + (q & 3) * 16;
  const size_t g1 = g0 + (size_t)64 * strideK;
  const int sld = tid << 4;

  f32x4 acc[8][4] = {};
  const int nkt = K >> 5;  // BK = 32

#define STAGE_AB(T)                                                       \
  {                                                                       \
    char* sb = lds + (((T) & 3) << 15);                                   \
    const char* ga = Ab + ((size_t)(T) << 6);                             \
    const char* gb = Bb + ((size_t)(T) << 6);                             \
    load_lds16(ga + g0, sb + sld);                                        \
    load_lds16(ga + g1, sb + 8192 + sld);                                 \
    load_lds16(gb + g0, sb + 16384 + sld);                                \
    load_lds16(gb + g1, sb + 24576 + sld);                                \
  }

#define MFMA_HALF(H, BF)                                                  \
  __builtin_amdgcn_s_setprio(1);                                          \
  _Pragma("unroll") for (int mm = 0; mm < 4; ++mm)                        \
      _Pragma("unroll") for (int nn = 0; nn < 4; ++nn)                    \
          acc[(H) + mm][nn] = __builtin_amdgcn_mfma_f32_16x16x32_bf16(    \
              a8[(H) + mm], BF[nn], acc[(H) + mm][nn], 0, 0, 0);          \
  __builtin_amdgcn_s_setprio(0);

// One K32-tile. Bc = current B frags (preloaded), Bn = next-tile B frags.
#define TILE(KT, Bc, Bn)                                                  \
  {                                                                       \
    const int kt_ = (KT);                                                 \
    const char* slot = lds + ((kt_ & 3) << 15);                           \
    bf16x8 a8[8];                                                         \
    _Pragma("unroll") for (int mm = 0; mm < 8; ++mm)                      \
        a8[mm] = *(const bf16x8*)(slot + aBase + (mm << 11));             \
    if (kt_ + 3 < nkt) STAGE_AB(kt_ + 3);                                 \
    if (kt_ < nkt - 3)                                                    \
      asm volatile("s_waitcnt vmcnt(8)" ::: "memory");                    \
    else if (kt_ == nkt - 3)                                              \
      asm volatile("s_waitcnt vmcnt(4)" ::: "memory");                    \
    else if (kt_ == nkt - 2)                                              \
      asm volatile("s_waitcnt vmcnt(0)" ::: "memory");                    \
    __builtin_amdgcn_s_barrier();                                         \
    asm volatile("" ::: "memory");                                        \
    if (kt_ + 1 < nkt) {                                                  \
      const char* sn = lds + (((kt_ + 1) & 3) << 15);                     \
      _Pragma("unroll") for (int nn = 0; nn < 4; ++nn)                    \
          Bn[nn] = *(const bf16x8*)(sn + bBase + (nn << 11));             \
    }                                                                     \
    MFMA_HALF(0, Bc)                                                      \
    MFMA_HALF(4, Bc)                                                      \
    __builtin_amdgcn_s_barrier();                                         \
    asm volatile("" ::: "memory");                                        \
  }

  // prologue: stage tiles 0..2; wait tile 0; preload B(0)
  STAGE_AB(0);
  STAGE_AB(1);
  STAGE_AB(2);
  asm volatile("s_waitcnt vmcnt(8)" ::: "memory");
  __builtin_amdgcn_s_barrier();
  asm volatile("" ::: "memory");

  bf16x8 bX[4], bY[4];
#pragma unroll
  for (int nn = 0; nn < 4; ++nn)
    bX[nn] = *(const bf16x8*)(lds + bBase + (nn << 11));

  for (int kt = 0; kt < nkt; kt += 2) {
    TILE(kt, bX, bY)
    TILE(kt + 1, bY, bX)
  }
#undef TILE
#undef STAGE_AB
#undef MFMA_HALF

  // epilogue: C/D layout col = lane&15, row = (lane>>4)*4 + reg  [m89-verified]
  const int cbase = tn * 256 + (wn << 6) + l15;
  float b4[4];
#pragma unroll
  for (int n = 0; n < 4; ++n) b4[n] = bias[cbase + (n << 4)];
  const size_t rbase = (size_t)tm * 256 + (wm << 7) + ((l >> 4) << 2);
#pragma unroll
  for (int m = 0; m < 8; ++m) {
#pragma unroll
    for (int j = 0; j < 4; ++j) {
      const size_t row = rbase + (m << 4) + j;
#pragma unroll
      for (int n = 0; n < 4; ++n) {
        const int col = cbase + (n << 4);
        float v = acc[m][n][j] + b4[n];
        if (OUT_F32)
          ((float*)Cout)[row * N + col] = v;
        else
          ((unsigned short*)Cout)[row * N + col] = f2bf(v);
      }
    }
  }
}

// ---------------------------------------------------------------- attention
// 16 lanes per (b,h); lane x handles dims 4x..4x+3 via ushort4 (8B/lane loads).
__global__ __launch_bounds__(256)
void attn_kernel(const unsigned short* __restrict__ QKV,  // (B*3) x 3072
                 const unsigned short* __restrict__ Cp,   // B x 1024
                 unsigned short* __restrict__ Out) {      // (B*3) x 1024
  const int t = threadIdx.x;
  const int grp = (blockIdx.x << 4) + (t >> 4);
  const int x = t & 15;
  const int b = grp >> 4;   // H = 16
  const int h = grp & 15;

  const size_t col = (size_t)h * 64 + (x << 2);
  const size_t qbase = (size_t)b * 3 * 3072 + col;

  ushort4 cu = *(const ushort4*)&Cp[(size_t)b * 1024 + col];
  float c[4] = {bf2f(cu.x), bf2f(cu.y), bf2f(cu.z), bf2f(cu.w)};

  float q[3][4], kc[3][4], vc[3][4];
#pragma unroll
  for (int i = 0; i < 3; ++i) {
    ushort4 qu = *(const ushort4*)&QKV[qbase + (size_t)i * 3072];
    ushort4 ku = *(const ushort4*)&QKV[qbase + (size_t)i * 3072 + 1024];
    ushort4 vu = *(const ushort4*)&QKV[qbase + (size_t)i * 3072 + 2048];
    q[i][0] = bf2f(qu.x); q[i][1] = bf2f(qu.y); q[i][2] = bf2f(qu.z); q[i][3] = bf2f(qu.w);
    kc[i][0] = bf2f(ku.x) * c[0]; kc[i][1] = bf2f(ku.y) * c[1];
    kc[i][2] = bf2f(ku.z) * c[2]; kc[i][3] = bf2f(ku.w) * c[3];
    vc[i][0] = bf2f(vu.x) * c[0]; vc[i][1] = bf2f(vu.y) * c[1];
    vc[i][2] = bf2f(vu.z) * c[2]; vc[i][3] = bf2f(vu.w) * c[3];
  }

  float s[9];
#pragma unroll
  for (int i = 0; i < 3; ++i)
#pragma unroll
    for (int j = 0; j < 3; ++j)
      s[i * 3 + j] = q[i][0] * kc[j][0] + q[i][1] * kc[j][1] +
                     q[i][2] * kc[j][2] + q[i][3] * kc[j][3];

#pragma unroll
  for (int off = 8; off > 0; off >>= 1)
#pragma unroll
    for (int e = 0; e < 9; ++e)
      s[e] += __shfl_xor(s[e], off, 64);

  const float scale = 0.125f;  // 1/sqrt(64)
#pragma unroll
  for (int i = 0; i < 3; ++i) {
    float s0 = s[i * 3 + 0] * scale;
    float s1 = s[i * 3 + 1] * scale;
    float s2 = s[i * 3 + 2] * scale;
    float m = fmaxf(fmaxf(s0, s1), s2);
    float p0 = expf(s0 - m), p1 = expf(s1 - m), p2 = expf(s2 - m);
    float inv = 1.0f / (p0 + p1 + p2);
    ushort4 o;
    o.x = f2bf((p0 * vc[0][0] + p1 * vc[1][0] + p2 * vc[2][0]) * inv);
    o.y = f2bf((p0 * vc[0][1] + p1 * vc[1][1] + p2 * vc[2][1]) * inv);
    o.z = f2bf((p0 * vc[0][2] + p1 * vc[1][2] + p2 * vc[2][2]) * inv);
    o.w = f2bf((p0 * vc[0][3] + p1 * vc[1][3] + p2 * vc[2][3]) * inv);
    *(ushort4*)&Out[(size_t)(b * 3 + i) * 1024 + col] = o;
  }
}

// ---------------------------------------------------------------- launch
extern "C" void kernel_launch(void* const* d_in, const int* in_sizes, int n_in,
                              void* d_out, int out_size, void* d_ws, size_t ws_size,
                              hipStream_t stream) {
  const float* tokens = (const float*)d_in[0];
  const float* ctx    = (const float*)d_in[1];
  const float* Wq     = (const float*)d_in[2];
  const float* bq     = (const float*)d_in[3];
  const float* Wk     = (const float*)d_in[4];
  const float* bk     = (const float*)d_in[5];
  const float* Wv     = (const float*)d_in[6];
  const float* bv     = (const float*)d_in[7];
  const float* Wc     = (const float*)d_in[8];
  const float* bc     = (const float*)d_in[9];
  const float* Wo     = (const float*)d_in[10];
  const float* bo     = (const float*)d_in[11];

  const int M  = BB * KK;   // 49152 token rows
  const int Mc = BB;        // 16384 ctx rows
  const int D  = DD;        // 1024

  char* p = (char*)d_ws;
  auto carve = [&](size_t bytes) {
    char* r = p;
    p += (bytes + 255) & ~(size_t)255;
    return r;
  };
  unsigned short* Xb   = (unsigned short*)carve((size_t)M * D * 2);  // tokens bf16; reused as attn out
  unsigned short* Cin  = (unsigned short*)carve((size_t)Mc * D * 2);
  unsigned short* Wqkv = (unsigned short*)carve((size_t)3 * D * D * 2);
  unsigned short* Wcb  = (unsigned short*)carve((size_t)D * D * 2);
  unsigned short* Wob  = (unsigned short*)carve((size_t)D * D * 2);
  float*          bqkv = (float*)carve((size_t)3 * D * 4);
  unsigned short* QKV  = (unsigned short*)carve((size_t)M * 3 * D * 2);
  unsigned short* Cpr  = (unsigned short*)carve((size_t)Mc * D * 2);

  hipLaunchKernelGGL(cast_f32_bf16, dim3(4096), dim3(256), 0, stream, tokens, Xb, M * D / 4);
  hipLaunchKernelGGL(cast_f32_bf16, dim3(2048), dim3(256), 0, stream, ctx, Cin, Mc * D / 4);
  hipLaunchKernelGGL(cast_f32_bf16, dim3(512), dim3(256), 0, stream, Wq, Wqkv, D * D / 4);
  hipLaunchKernelGGL(cast_f32_bf16, dim3(512), dim3(256), 0, stream, Wk, Wqkv + D * D, D * D / 4);
  hipLaunchKernelGGL(cast_f32_bf16, dim3(512), dim3(256), 0, stream, Wv, Wqkv + 2 * D * D, D * D / 4);
  hipLaunchKernelGGL(cast_f32_bf16, dim3(512), dim3(256), 0, stream, Wc, Wcb, D * D / 4);
  hipLaunchKernelGGL(cast_f32_bf16, dim3(512), dim3(256), 0, stream, Wo, Wob, D * D / 4);
  hipMemcpyAsync(bqkv, bq, D * 4, hipMemcpyDeviceToDevice, stream);
  hipMemcpyAsync(bqkv + D, bk, D * 4, hipMemcpyDeviceToDevice, stream);
  hipMemcpyAsync(bqkv + 2 * D, bv, D * 4, hipMemcpyDeviceToDevice, stream);

  // QKV projection: (49152 x 1024) @ (1024 x 3072) -> 192*12 = 2304 blocks
  hipLaunchKernelGGL((gemm256<false>), dim3((M / 256) * (3 * D / 256)), dim3(512), 0, stream,
                     (const __hip_bfloat16*)Xb, (const __hip_bfloat16*)Wqkv, bqkv,
                     (void*)QKV, M, 3 * D, D);
  // ctx projection: (16384 x 1024) @ (1024 x 1024) -> 64*4 = 256 blocks
  hipLaunchKernelGGL((gemm256<false>), dim3((Mc / 256) * (D / 256)), dim3(512), 0, stream,
                     (const __hip_bfloat16*)Cin, (const __hip_bfloat16*)Wcb, bc,
                     (void*)Cpr, Mc, D, D);
  // attention (writes into Xb, dead after the QKV GEMM)
  hipLaunchKernelGGL(attn_kernel, dim3(BB * HH / 16), dim3(256), 0, stream, QKV, Cpr, Xb);
  // output projection -> fp32 d_out with bias: 192*4 = 768 blocks
  hipLaunchKernelGGL((gemm256<true>), dim3((M / 256) * (D / 256)), dim3(512), 0, stream,
                     (const __hip_bfloat16*)Xb, (const __hip_bfloat16*)Wob, bo,
                     d_out, M, D, D);
}